// Round 2
// baseline (4991.083 us; speedup 1.0000x reference)
//
#include <hip/hip_runtime.h>
#include <math.h>

#define LEAKY 0.2f
#define BN_EPS 1e-5f

// ---- monotone float<->uint encoding for atomicMax on floats ----
__device__ __forceinline__ unsigned enc_ord(float x){
    unsigned u = __float_as_uint(x);
    return (u & 0x80000000u) ? ~u : (u | 0x80000000u);
}
__device__ __forceinline__ float dec_ord(unsigned u){
    unsigned b = (u & 0x80000000u) ? (u ^ 0x80000000u) : ~u;
    return __uint_as_float(b);
}

// encoder: z[n,j] = sum_k x[n,k]*W[k,j] + b[j]   (K=7, M=64)
__global__ __launch_bounds__(256) void k_encoder(const float* __restrict__ x,
        const float* __restrict__ W, const float* __restrict__ b,
        float* __restrict__ z, int N){
    int gid = blockIdx.x*256 + threadIdx.x;
    int n = gid >> 6, j = gid & 63;
    if (n >= N) return;
    float acc = b[j];
    #pragma unroll
    for (int k=0;k<7;k++) acc += x[n*7+k]*W[k*64+j];
    z[(size_t)n*64+j] = acc;
}

// generic linear: h[N,M] = z[N,K] @ W[K,M]
template<int K, int M>
__global__ __launch_bounds__(256) void k_linear(const float* __restrict__ z,
        const float* __restrict__ W, float* __restrict__ h, int N){
    int gid = blockIdx.x*256 + threadIdx.x;
    int n = gid / M, j = gid % M;
    if (n >= N) return;
    float acc = 0.f;
    #pragma unroll 8
    for (int k=0;k<K;k++) acc += z[(size_t)n*K+k]*W[k*M+j];
    h[(size_t)n*M+j] = acc;
}

// attention logits: al_s[n,h] = dot(h[n,h,:], a_src[h,:]) ; same for dst
template<int H, int C>
__global__ __launch_bounds__(256) void k_att(const float* __restrict__ hf,
        const float* __restrict__ a_src, const float* __restrict__ a_dst,
        float* __restrict__ al_s, float* __restrict__ al_d, int N){
    int gid = blockIdx.x*256 + threadIdx.x;
    int n = gid / H, hh = gid % H;
    if (n >= N) return;
    const float* hr = hf + (size_t)n*(H*C) + hh*C;
    float s=0.f, d=0.f;
    #pragma unroll
    for (int c=0;c<C;c++){ float v = hr[c]; s += v*a_src[hh*C+c]; d += v*a_dst[hh*C+c]; }
    al_s[(size_t)n*H+hh]=s; al_d[(size_t)n*H+hh]=d;
}

// pass 1: segment max over dst (includes self-loops as edges E..E+N-1)
template<int H>
__global__ __launch_bounds__(256) void k_edge_max(const int* __restrict__ ei, int E, int N,
        const float* __restrict__ al_s, const float* __restrict__ al_d,
        unsigned* __restrict__ m){
    int gid = blockIdx.x*256 + threadIdx.x;
    int e = gid / H, hh = gid % H;
    if (e >= E + N) return;
    int s, d;
    if (e < E){ s = ei[e]; d = ei[E+e]; } else { s = d = e - E; }
    float v = al_s[(size_t)s*H+hh] + al_d[(size_t)d*H+hh];
    v = v > 0.f ? v : LEAKY*v;
    atomicMax(m + (size_t)d*H + hh, enc_ord(v));
}

// pass 2: ex = exp(e - m[dst]); acc[dst,j] += h[src,j]*ex ; denom[dst,h] += ex
template<int H, int C>
__global__ __launch_bounds__(256) void k_edge_scatter(const int* __restrict__ ei, int E, int N,
        const float* __restrict__ al_s, const float* __restrict__ al_d,
        const unsigned* __restrict__ m, const float* __restrict__ hfeat,
        float* __restrict__ acc, float* __restrict__ denom){
    const int M = H*C;
    unsigned gid = blockIdx.x*256u + threadIdx.x;
    unsigned e = gid / (unsigned)M; int j = gid % (unsigned)M;
    if (e >= (unsigned)(E + N)) return;
    int hh = j / C;
    int s, d;
    if (e < (unsigned)E){ s = ei[e]; d = ei[E+e]; } else { s = d = (int)(e - E); }
    float v = al_s[(size_t)s*H+hh] + al_d[(size_t)d*H+hh];
    v = v > 0.f ? v : LEAKY*v;
    float ex = __expf(v - dec_ord(m[(size_t)d*H+hh]));
    if ((j & (C-1)) == 0) atomicAdd(denom + (size_t)d*H + hh, ex);
    atomicAdd(acc + (size_t)d*M + j, hfeat[(size_t)s*M + j]*ex);
}

// node epilogue: z = acc/denom + b; optional BN column stats (block-reduced)
template<int H, int C, bool STATS>
__global__ void k_finalize(const float* __restrict__ acc, const float* __restrict__ denom,
        const float* __restrict__ b, float* __restrict__ z,
        float* __restrict__ cs, float* __restrict__ cq, int N){
    const int M = H*C;
    int j = threadIdx.x;            // blockDim.x == M
    int hh = j / C;
    float bj = b[j];
    float lsum = 0.f, lsq = 0.f;
    for (int n = blockIdx.x; n < N; n += gridDim.x){
        float v = acc[(size_t)n*M+j] / (denom[(size_t)n*H+hh] + 1e-16f) + bj;
        z[(size_t)n*M+j] = v;
        if (STATS){ lsum += v; lsq += v*v; }
    }
    if (STATS){ atomicAdd(cs+j, lsum); atomicAdd(cq+j, lsq); }
}

// BN (batch stats, biased var) + ReLU, in place on z[N,128]
__global__ __launch_bounds__(256) void k_bn_relu(float* __restrict__ z,
        const float* __restrict__ gamma, const float* __restrict__ beta,
        const float* __restrict__ cs, const float* __restrict__ cq, int N){
    int gid = blockIdx.x*256 + threadIdx.x;
    int n = gid >> 7, j = gid & 127;
    if (n >= N) return;
    float invN = 1.f / (float)N;
    float mu = cs[j]*invN;
    float var = cq[j]*invN - mu*mu;
    float v = gamma[j]*(z[(size_t)n*128+j]-mu)*rsqrtf(var+BN_EPS)+beta[j];
    z[(size_t)n*128+j] = v > 0.f ? v : 0.f;
}

// decoder: out[n,o] = dot(z[n,:64], dec_W[:,o]) + dec_b[o]
__global__ __launch_bounds__(256) void k_decoder(const float* __restrict__ z,
        const float* __restrict__ W, const float* __restrict__ b,
        float* __restrict__ out, int N){
    int gid = blockIdx.x*256 + threadIdx.x;
    int n = gid >> 2, o = gid & 3;
    if (n >= N) return;
    float acc = b[o];
    #pragma unroll
    for (int k=0;k<64;k++) acc += z[(size_t)n*64+k]*W[k*4+o];
    out[(size_t)n*4+o] = acc;
}

extern "C" void kernel_launch(void* const* d_in, const int* in_sizes, int n_in,
                              void* d_out, int out_size, void* d_ws, size_t ws_size,
                              hipStream_t stream){
    const float* x      = (const float*)d_in[0];
    const int*   ei     = (const int*)  d_in[1];
    const float* enc_W  = (const float*)d_in[2];
    const float* enc_b  = (const float*)d_in[3];
    const float* in_W   = (const float*)d_in[4];
    const float* in_as  = (const float*)d_in[5];
    const float* in_ad  = (const float*)d_in[6];
    const float* in_b   = (const float*)d_in[7];
    const float* hid_W  = (const float*)d_in[8];
    const float* hid_as = (const float*)d_in[9];
    const float* hid_ad = (const float*)d_in[10];
    const float* hid_b  = (const float*)d_in[11];
    const float* bn_g   = (const float*)d_in[12];
    const float* bn_b   = (const float*)d_in[13];
    const float* out_W  = (const float*)d_in[14];
    const float* out_as = (const float*)d_in[15];
    const float* out_ad = (const float*)d_in[16];
    const float* out_b  = (const float*)d_in[17];
    const float* dec_W  = (const float*)d_in[18];
    const float* dec_b  = (const float*)d_in[19];

    const int N = in_sizes[0] / 7;
    const int E = in_sizes[1] / 2;
    const int ET = E + N;                       // edges + self loops

    // workspace layout (fp32):
    float*    bufZ = (float*)d_ws;              // [N,128] layer activations
    float*    bufH = bufZ + (size_t)N*128;      // [N,128] h = z@W
    float*    bufA = bufH + (size_t)N*128;      // [N,128] scatter accumulator
    float*    al_s = bufA + (size_t)N*128;      // [N,4]
    float*    al_d = al_s + (size_t)N*4;        // [N,4]
    unsigned* mE   = (unsigned*)(al_d + (size_t)N*4); // [N,4] encoded max
    float*    den  = (float*)mE + (size_t)N*4;  // [N,4]
    float*    cs   = den + (size_t)N*4;         // [128] col sums
    float*    cq   = cs + 128;                  // [128] col sumsq

    auto clear = [&](int M){
        hipMemsetAsync(bufA, 0, (size_t)N*M*sizeof(float), stream);
        hipMemsetAsync(mE,   0, (size_t)N*4*2*sizeof(unsigned), stream); // mE + den
        hipMemsetAsync(cs,   0, 256*sizeof(float), stream);              // cs + cq
    };

    // ---- encoder ----
    k_encoder<<<(N*64+255)/256, 256, 0, stream>>>(x, enc_W, enc_b, bufZ, N);

    // ---- GAT layer 1: K=64 -> 4x32, BN idx 0 ----
    k_linear<64,128><<<((size_t)N*128+255)/256, 256, 0, stream>>>(bufZ, in_W, bufH, N);
    k_att<4,32><<<(N*4+255)/256, 256, 0, stream>>>(bufH, in_as, in_ad, al_s, al_d, N);
    clear(128);
    k_edge_max<4><<<((size_t)ET*4+255)/256, 256, 0, stream>>>(ei, E, N, al_s, al_d, mE);
    k_edge_scatter<4,32><<<((size_t)ET*128+255)/256, 256, 0, stream>>>(ei, E, N, al_s, al_d, mE, bufH, bufA, den);
    k_finalize<4,32,true><<<1024, 128, 0, stream>>>(bufA, den, in_b, bufZ, cs, cq, N);
    k_bn_relu<<<((size_t)N*128+255)/256, 256, 0, stream>>>(bufZ, bn_g, bn_b, cs, cq, N);

    // ---- hidden GAT layers ----
    for (int i = 0; i < 2; i++){
        const float* W  = hid_W  + (size_t)i*128*128;
        const float* as = hid_as + (size_t)i*128;
        const float* ad = hid_ad + (size_t)i*128;
        const float* bb = hid_b  + (size_t)i*128;
        k_linear<128,128><<<((size_t)N*128+255)/256, 256, 0, stream>>>(bufZ, W, bufH, N);
        k_att<4,32><<<(N*4+255)/256, 256, 0, stream>>>(bufH, as, ad, al_s, al_d, N);
        clear(128);
        k_edge_max<4><<<((size_t)ET*4+255)/256, 256, 0, stream>>>(ei, E, N, al_s, al_d, mE);
        k_edge_scatter<4,32><<<((size_t)ET*128+255)/256, 256, 0, stream>>>(ei, E, N, al_s, al_d, mE, bufH, bufA, den);
        k_finalize<4,32,true><<<1024, 128, 0, stream>>>(bufA, den, bb, bufZ, cs, cq, N);
        k_bn_relu<<<((size_t)N*128+255)/256, 256, 0, stream>>>(bufZ, bn_g + (i+1)*128, bn_b + (i+1)*128, cs, cq, N);
    }

    // ---- out GAT layer: K=128 -> 1x64 (concat=False, 1 head == identity mean) ----
    k_linear<128,64><<<((size_t)N*64+255)/256, 256, 0, stream>>>(bufZ, out_W, bufH, N);
    k_att<1,64><<<(N+255)/256, 256, 0, stream>>>(bufH, out_as, out_ad, al_s, al_d, N);
    clear(64);
    k_edge_max<1><<<(ET+255)/256, 256, 0, stream>>>(ei, E, N, al_s, al_d, mE);
    k_edge_scatter<1,64><<<((size_t)ET*64+255)/256, 256, 0, stream>>>(ei, E, N, al_s, al_d, mE, bufH, bufA, den);
    k_finalize<1,64,false><<<1024, 64, 0, stream>>>(bufA, den, out_b, bufZ, nullptr, nullptr, N);

    // ---- decoder ----
    k_decoder<<<((size_t)N*4+255)/256, 256, 0, stream>>>(bufZ, dec_W, dec_b, (float*)d_out, N);
}

// Round 3
// 2310.692 us; speedup vs baseline: 2.1600x; 2.1600x over previous
//
#include <hip/hip_runtime.h>
#include <math.h>

#define LEAKY 0.2f
#define BN_EPS 1e-5f

// ---------------- dense layers ----------------

// encoder: z[n,j] = sum_k x[n,k]*W[k,j] + b[j]   (K=7, M=64)
__global__ __launch_bounds__(256) void k_encoder(const float* __restrict__ x,
        const float* __restrict__ W, const float* __restrict__ b,
        float* __restrict__ z, int N){
    int gid = blockIdx.x*256 + threadIdx.x;
    int n = gid >> 6, j = gid & 63;
    if (n >= N) return;
    float acc = b[j];
    #pragma unroll
    for (int k=0;k<7;k++) acc += x[n*7+k]*W[k*64+j];
    z[(size_t)n*64+j] = acc;
}

// generic linear: h[N,M] = z[N,K] @ W[K,M]
template<int K, int M>
__global__ __launch_bounds__(256) void k_linear(const float* __restrict__ z,
        const float* __restrict__ W, float* __restrict__ h, int N){
    int gid = blockIdx.x*256 + threadIdx.x;
    int n = gid / M, j = gid % M;
    if (n >= N) return;
    float acc = 0.f;
    #pragma unroll 8
    for (int k=0;k<K;k++) acc += z[(size_t)n*K+k]*W[k*M+j];
    h[(size_t)n*M+j] = acc;
}

// attention logits: al_s[n,h] = dot(h[n,h,:], a_src[h,:]) ; same for dst
template<int H, int C>
__global__ __launch_bounds__(256) void k_att(const float* __restrict__ hf,
        const float* __restrict__ a_src, const float* __restrict__ a_dst,
        float* __restrict__ al_s, float* __restrict__ al_d, int N){
    int gid = blockIdx.x*256 + threadIdx.x;
    int n = gid / H, hh = gid % H;
    if (n >= N) return;
    const float* hr = hf + (size_t)n*(H*C) + hh*C;
    float s=0.f, d=0.f;
    #pragma unroll
    for (int c=0;c<C;c++){ float v = hr[c]; s += v*a_src[hh*C+c]; d += v*a_dst[hh*C+c]; }
    al_s[(size_t)n*H+hh]=s; al_d[(size_t)n*H+hh]=d;
}

// ---------------- CSR build (once per call, reused by all 4 GAT layers) ----------------

__global__ __launch_bounds__(256) void k_deg(const int* __restrict__ ei, int E,
        int* __restrict__ deg){
    int e = blockIdx.x*256 + threadIdx.x;
    if (e < E) atomicAdd(deg + ei[E+e], 1);
}

__device__ __forceinline__ int wave_scan(int v, int lane){
    #pragma unroll
    for (int off=1; off<64; off<<=1){
        int t = __shfl_up(v, off, 64);
        if (lane >= off) v += t;
    }
    return v;
}

// per-1024-block inclusive scan -> exclusive values + block totals
__global__ __launch_bounds__(1024) void k_scan1(const int* __restrict__ deg,
        int* __restrict__ excl, int* __restrict__ bsum, int N){
    __shared__ int ws[16];
    int i = blockIdx.x*1024 + threadIdx.x;
    int lane = threadIdx.x & 63, wid = threadIdx.x >> 6;
    int v = (i < N) ? deg[i] : 0;
    int inc = wave_scan(v, lane);
    if (lane == 63) ws[wid] = inc;
    __syncthreads();
    if (wid == 0){
        int wv = (lane < 16) ? ws[lane] : 0;
        int winc = wave_scan(wv, lane);
        if (lane < 16) ws[lane] = winc - wv;   // exclusive wave offsets
    }
    __syncthreads();
    int off = ws[wid];
    if (i < N) excl[i] = off + inc - v;
    if (threadIdx.x == 1023) bsum[blockIdx.x] = off + inc;  // block total
}

// exclusive scan of block sums (nb ~ 98) — single thread, once per call
__global__ void k_scan2(int* __restrict__ bsum, int nb){
    if (threadIdx.x == 0 && blockIdx.x == 0){
        int c = 0;
        for (int i = 0; i < nb; i++){ int t = bsum[i]; bsum[i] = c; c += t; }
    }
}

__global__ __launch_bounds__(256) void k_scan3(const int* __restrict__ excl,
        const int* __restrict__ bsum, int* __restrict__ rowptr,
        int* __restrict__ cursor, int N, int E){
    int i = blockIdx.x*256 + threadIdx.x;
    if (i < N){
        int r = excl[i] + bsum[i >> 10];
        rowptr[i] = r; cursor[i] = r;
    } else if (i == N){
        rowptr[N] = E;
    }
}

__global__ __launch_bounds__(256) void k_bucket(const int* __restrict__ ei, int E,
        int* __restrict__ cursor, int* __restrict__ csr){
    int e = blockIdx.x*256 + threadIdx.x;
    if (e >= E) return;
    int pos = atomicAdd(cursor + ei[E+e], 1);
    csr[pos] = ei[e];
}

// ---------------- GAT aggregation: one wave per dst, online softmax in registers ----------------

template<int H, int C>
__global__ __launch_bounds__(256) void k_gat_agg(
        const int* __restrict__ rowptr, const int* __restrict__ csr_src,
        const float* __restrict__ al_s, const float* __restrict__ al_d,
        const float* __restrict__ hfeat, const float* __restrict__ b,
        float* __restrict__ z, int N)
{
    constexpr int M = H*C;
    constexpr int EL = M/64;                 // features per lane (2 or 1)
    int dst = (blockIdx.x*blockDim.x + threadIdx.x) >> 6;
    if (dst >= N) return;
    int lane = threadIdx.x & 63;
    int j = EL*lane;
    int h = j / C;                            // both features of a lane share a head
    float ald = al_d[(size_t)dst*H + h];

    // self-loop seeds the online softmax
    float v0 = al_s[(size_t)dst*H + h] + ald;
    v0 = v0 > 0.f ? v0 : LEAKY*v0;
    float m = v0, s = 1.f;
    float acc0, acc1 = 0.f;
    if (EL == 2){
        float2 hv = *(const float2*)(hfeat + (size_t)dst*M + j);
        acc0 = hv.x; acc1 = hv.y;
    } else {
        acc0 = hfeat[(size_t)dst*M + j];
    }

    int p1 = rowptr[dst+1];
    for (int p = rowptr[dst]; p < p1; ++p){
        int src = csr_src[p];
        float vv = al_s[(size_t)src*H + h] + ald;
        vv = vv > 0.f ? vv : LEAKY*vv;
        float mx = fmaxf(m, vv);
        float sc = __expf(m - mx);
        float ex = __expf(vv - mx);
        m = mx;
        s = s*sc + ex;
        if (EL == 2){
            float2 hv = *(const float2*)(hfeat + (size_t)src*M + j);
            acc0 = acc0*sc + hv.x*ex;
            acc1 = acc1*sc + hv.y*ex;
        } else {
            acc0 = acc0*sc + hfeat[(size_t)src*M + j]*ex;
        }
    }
    float inv = 1.f/(s + 1e-16f);
    if (EL == 2){
        z[(size_t)dst*M + j]     = acc0*inv + b[j];
        z[(size_t)dst*M + j + 1] = acc1*inv + b[j+1];
    } else {
        z[(size_t)dst*M + j] = acc0*inv + b[j];
    }
}

// ---------------- BN ----------------

// column sums/sumsq of z[N,128]; grid-stride, one atomic per (block,col)
__global__ void k_bn_stats(const float* __restrict__ z,
        float* __restrict__ cs, float* __restrict__ cq, int N){
    int j = threadIdx.x;                     // blockDim.x == 128
    float ls = 0.f, lq = 0.f;
    for (int n = blockIdx.x; n < N; n += gridDim.x){
        float v = z[(size_t)n*128 + j]; ls += v; lq += v*v;
    }
    atomicAdd(cs + j, ls); atomicAdd(cq + j, lq);
}

// BN (batch stats, biased var) + ReLU, in place on z[N,128]
__global__ __launch_bounds__(256) void k_bn_relu(float* __restrict__ z,
        const float* __restrict__ gamma, const float* __restrict__ beta,
        const float* __restrict__ cs, const float* __restrict__ cq, int N){
    int gid = blockIdx.x*256 + threadIdx.x;
    int n = gid >> 7, j = gid & 127;
    if (n >= N) return;
    float invN = 1.f / (float)N;
    float mu = cs[j]*invN;
    float var = cq[j]*invN - mu*mu;
    float v = gamma[j]*(z[(size_t)n*128+j]-mu)*rsqrtf(var+BN_EPS)+beta[j];
    z[(size_t)n*128+j] = v > 0.f ? v : 0.f;
}

// decoder: out[n,o] = dot(z[n,:64], dec_W[:,o]) + dec_b[o]
__global__ __launch_bounds__(256) void k_decoder(const float* __restrict__ z,
        const float* __restrict__ W, const float* __restrict__ b,
        float* __restrict__ out, int N){
    int gid = blockIdx.x*256 + threadIdx.x;
    int n = gid >> 2, o = gid & 3;
    if (n >= N) return;
    float acc = b[o];
    #pragma unroll
    for (int k=0;k<64;k++) acc += z[(size_t)n*64+k]*W[k*4+o];
    out[(size_t)n*4+o] = acc;
}

extern "C" void kernel_launch(void* const* d_in, const int* in_sizes, int n_in,
                              void* d_out, int out_size, void* d_ws, size_t ws_size,
                              hipStream_t stream){
    const float* x      = (const float*)d_in[0];
    const int*   ei     = (const int*)  d_in[1];
    const float* enc_W  = (const float*)d_in[2];
    const float* enc_b  = (const float*)d_in[3];
    const float* in_W   = (const float*)d_in[4];
    const float* in_as  = (const float*)d_in[5];
    const float* in_ad  = (const float*)d_in[6];
    const float* in_b   = (const float*)d_in[7];
    const float* hid_W  = (const float*)d_in[8];
    const float* hid_as = (const float*)d_in[9];
    const float* hid_ad = (const float*)d_in[10];
    const float* hid_b  = (const float*)d_in[11];
    const float* bn_g   = (const float*)d_in[12];
    const float* bn_b   = (const float*)d_in[13];
    const float* out_W  = (const float*)d_in[14];
    const float* out_as = (const float*)d_in[15];
    const float* out_ad = (const float*)d_in[16];
    const float* out_b  = (const float*)d_in[17];
    const float* dec_W  = (const float*)d_in[18];
    const float* dec_b  = (const float*)d_in[19];

    const int N = in_sizes[0] / 7;
    const int E = in_sizes[1] / 2;
    const int NB = (N + 1023) / 1024;

    // workspace layout (fp32 / int32):
    float*    bufZ   = (float*)d_ws;                  // [N,128]
    float*    bufH   = bufZ + (size_t)N*128;          // [N,128]
    float*    al_s   = bufH + (size_t)N*128;          // [N,4]
    float*    al_d   = al_s + (size_t)N*4;            // [N,4]
    float*    cs     = al_d + (size_t)N*4;            // [128]
    float*    cq     = cs + 128;                      // [128]
    int*      deg    = (int*)(cq + 128);              // [N]
    int*      excl   = deg + N;                       // [N]
    int*      rowptr = excl + N;                      // [N+1]
    int*      cursor = rowptr + (N+1);                // [N]
    int*      bsum   = cursor + N;                    // [NB]
    int*      csr    = bsum + NB;                     // [E]

    // ---- CSR build (by dst; self-loops handled inline in k_gat_agg) ----
    hipMemsetAsync(deg, 0, (size_t)N*sizeof(int), stream);
    k_deg   <<<(E+255)/256, 256, 0, stream>>>(ei, E, deg);
    k_scan1 <<<NB, 1024, 0, stream>>>(deg, excl, bsum, N);
    k_scan2 <<<1, 64, 0, stream>>>(bsum, NB);
    k_scan3 <<<(N+1+255)/256, 256, 0, stream>>>(excl, bsum, rowptr, cursor, N, E);
    k_bucket<<<(E+255)/256, 256, 0, stream>>>(ei, E, cursor, csr);

    // ---- encoder ----
    k_encoder<<<(N*64+255)/256, 256, 0, stream>>>(x, enc_W, enc_b, bufZ, N);

    // ---- GAT layer 1: K=64 -> 4x32, BN idx 0 ----
    k_linear<64,128><<<((size_t)N*128+255)/256, 256, 0, stream>>>(bufZ, in_W, bufH, N);
    k_att<4,32><<<(N*4+255)/256, 256, 0, stream>>>(bufH, in_as, in_ad, al_s, al_d, N);
    k_gat_agg<4,32><<<((size_t)N*64+255)/256, 256, 0, stream>>>(rowptr, csr, al_s, al_d, bufH, in_b, bufZ, N);
    hipMemsetAsync(cs, 0, 256*sizeof(float), stream);
    k_bn_stats<<<1024, 128, 0, stream>>>(bufZ, cs, cq, N);
    k_bn_relu<<<((size_t)N*128+255)/256, 256, 0, stream>>>(bufZ, bn_g, bn_b, cs, cq, N);

    // ---- hidden GAT layers ----
    for (int i = 0; i < 2; i++){
        const float* W  = hid_W  + (size_t)i*128*128;
        const float* as = hid_as + (size_t)i*128;
        const float* ad = hid_ad + (size_t)i*128;
        const float* bb = hid_b  + (size_t)i*128;
        k_linear<128,128><<<((size_t)N*128+255)/256, 256, 0, stream>>>(bufZ, W, bufH, N);
        k_att<4,32><<<(N*4+255)/256, 256, 0, stream>>>(bufH, as, ad, al_s, al_d, N);
        k_gat_agg<4,32><<<((size_t)N*64+255)/256, 256, 0, stream>>>(rowptr, csr, al_s, al_d, bufH, bb, bufZ, N);
        hipMemsetAsync(cs, 0, 256*sizeof(float), stream);
        k_bn_stats<<<1024, 128, 0, stream>>>(bufZ, cs, cq, N);
        k_bn_relu<<<((size_t)N*128+255)/256, 256, 0, stream>>>(bufZ, bn_g + (i+1)*128, bn_b + (i+1)*128, cs, cq, N);
    }

    // ---- out GAT layer: K=128 -> 1x64 (concat=False, 1 head) ----
    k_linear<128,64><<<((size_t)N*64+255)/256, 256, 0, stream>>>(bufZ, out_W, bufH, N);
    k_att<1,64><<<(N+255)/256, 256, 0, stream>>>(bufH, out_as, out_ad, al_s, al_d, N);
    k_gat_agg<1,64><<<((size_t)N*64+255)/256, 256, 0, stream>>>(rowptr, csr, al_s, al_d, bufH, out_b, bufZ, N);

    // ---- decoder ----
    k_decoder<<<((size_t)N*4+255)/256, 256, 0, stream>>>(bufZ, dec_W, dec_b, (float*)d_out, N);
}

// Round 4
// 1352.580 us; speedup vs baseline: 3.6900x; 1.7084x over previous
//
#include <hip/hip_runtime.h>
#include <math.h>

#define LEAKY 0.2f
#define BN_EPS 1e-5f

typedef unsigned short u16;
typedef __bf16 bf16x8 __attribute__((ext_vector_type(8)));
typedef float f32x4 __attribute__((ext_vector_type(4)));
typedef u16 ushort8 __attribute__((ext_vector_type(8)));

__device__ __forceinline__ u16 f2bf(float x){
    unsigned u = __float_as_uint(x);
    u += 0x7FFFu + ((u >> 16) & 1u);          // RNE (finite data, no NaN)
    return (u16)(u >> 16);
}
__device__ __forceinline__ float bf2f(u16 b){ return __uint_as_float(((unsigned)b) << 16); }

// ---------------- dense layers ----------------

// encoder: z[n,j] = sum_k x[n,k]*W[k,j] + b[j]   (K=7, M=64)
__global__ __launch_bounds__(256) void k_encoder(const float* __restrict__ x,
        const float* __restrict__ W, const float* __restrict__ b,
        float* __restrict__ z, int N){
    int gid = blockIdx.x*256 + threadIdx.x;
    int n = gid >> 6, j = gid & 63;
    if (n >= N) return;
    float acc = b[j];
    #pragma unroll
    for (int k=0;k<7;k++) acc += x[n*7+k]*W[k*64+j];
    z[(size_t)n*64+j] = acc;
}

// pack W[K][M] fp32 -> hi/lo bf16 in MFMA B-fragment layout:
// idx = ((t*M + n)*4 + l16)*8 + e, where k = t*32 + l16*8 + e
template<int K, int M>
__global__ __launch_bounds__(256) void k_pack_w(const float* __restrict__ W,
        u16* __restrict__ hi, u16* __restrict__ lo){
    int idx = blockIdx.x*256 + threadIdx.x;
    if (idx >= K*M) return;
    int e = idx & 7, l16 = (idx >> 3) & 3, rest = idx >> 5;
    int n = rest % M, t = rest / M;
    int k = t*32 + l16*8 + e;
    float w = W[(size_t)k*M + n];
    u16 hb = f2bf(w);
    hi[idx] = hb;
    lo[idx] = f2bf(w - bf2f(hb));
}

// split-bf16 MFMA GEMM: h[N,M] = z[N,K] @ W[K,M]  (fp32-equivalent precision)
// block: 256 thr = 4 waves (RW x CW), tile 64 rows x M cols; wave: WR x WC fragments
template<int K, int M, int RW, int CW, int WR, int WC>
__global__ __launch_bounds__(256) void k_gemm(const float* __restrict__ z,
        const u16* __restrict__ Whi, const u16* __restrict__ Wlo,
        float* __restrict__ h, int N)
{
    static_assert(RW*CW == 4 && RW*WR*16 == 64 && CW*WC*16 == M, "tile config");
    constexpr int KS = K/32;
    constexpr int KG = K/8;
    __shared__ __align__(16) u16 Ahi[64*K];
    __shared__ __align__(16) u16 Alo[64*K];
    const int brow = blockIdx.x*64;
    const int tid = threadIdx.x;

    // stage A-tile: fp32 -> hi/lo bf16, fragment layout ((rb*KS+t)*64 + lane)*8 + e
    for (int u = tid; u < 64*KG; u += 256){
        int row = u / KG, kg = u % KG;
        int gr = brow + row;
        float v[8];
        if (gr < N){
            const float4* p = (const float4*)(z + (size_t)gr*K + kg*8);
            float4 a = p[0], bq = p[1];
            v[0]=a.x; v[1]=a.y; v[2]=a.z; v[3]=a.w;
            v[4]=bq.x; v[5]=bq.y; v[6]=bq.z; v[7]=bq.w;
        } else {
            #pragma unroll
            for (int e=0;e<8;e++) v[e]=0.f;
        }
        ushort8 h8, l8;
        #pragma unroll
        for (int e=0;e<8;e++){
            u16 hb = f2bf(v[e]);
            h8[e] = hb;
            l8[e] = f2bf(v[e] - bf2f(hb));
        }
        int rb = row >> 4, t = kg >> 2, lg = kg & 3;
        int base = (((rb*KS + t)*64) + (row & 15) + 16*lg)*8;
        *(ushort8*)&Ahi[base] = h8;
        *(ushort8*)&Alo[base] = l8;
    }
    __syncthreads();

    const int wave = tid >> 6, lane = tid & 63;
    const int wrow = wave / CW, wcol = wave % CW;
    const int l15 = lane & 15, l16 = lane >> 4;

    f32x4 acc[WR][WC];
    #pragma unroll
    for (int r=0;r<WR;r++)
        #pragma unroll
        for (int c=0;c<WC;c++) acc[r][c] = (f32x4){0.f,0.f,0.f,0.f};

    #pragma unroll
    for (int t = 0; t < KS; ++t){
        bf16x8 ah[WR], al[WR];
        #pragma unroll
        for (int r=0;r<WR;r++){
            int rb = wrow*WR + r;
            int off = ((rb*KS + t)*64 + lane)*8;
            ah[r] = *(const bf16x8*)&Ahi[off];
            al[r] = *(const bf16x8*)&Alo[off];
        }
        bf16x8 bh[WC], bl[WC];
        #pragma unroll
        for (int c=0;c<WC;c++){
            int n = (wcol*WC + c)*16 + l15;
            size_t off = ((size_t)(t*M + n)*4 + (size_t)l16)*8;
            bh[c] = *(const bf16x8*)&Whi[off];
            bl[c] = *(const bf16x8*)&Wlo[off];
        }
        #pragma unroll
        for (int r=0;r<WR;r++)
            #pragma unroll
            for (int c=0;c<WC;c++){
                acc[r][c] = __builtin_amdgcn_mfma_f32_16x16x32_bf16(al[r], bh[c], acc[r][c], 0,0,0);
                acc[r][c] = __builtin_amdgcn_mfma_f32_16x16x32_bf16(ah[r], bl[c], acc[r][c], 0,0,0);
                acc[r][c] = __builtin_amdgcn_mfma_f32_16x16x32_bf16(ah[r], bh[c], acc[r][c], 0,0,0);
            }
    }

    #pragma unroll
    for (int r=0;r<WR;r++)
        #pragma unroll
        for (int c=0;c<WC;c++){
            int colg = (wcol*WC + c)*16 + l15;
            #pragma unroll
            for (int q=0;q<4;q++){
                int rowg = brow + (wrow*WR + r)*16 + l16*4 + q;
                if (rowg < N) h[(size_t)rowg*M + colg] = acc[r][c][q];
            }
        }
}

// attention logits: al_s[n,h] = dot(h[n,h,:], a_src[h,:]) ; same for dst
template<int H, int C>
__global__ __launch_bounds__(256) void k_att(const float* __restrict__ hf,
        const float* __restrict__ a_src, const float* __restrict__ a_dst,
        float* __restrict__ al_s, float* __restrict__ al_d, int N){
    int gid = blockIdx.x*256 + threadIdx.x;
    int n = gid / H, hh = gid % H;
    if (n >= N) return;
    const float* hr = hf + (size_t)n*(H*C) + hh*C;
    float s=0.f, d=0.f;
    #pragma unroll
    for (int c=0;c<C;c++){ float v = hr[c]; s += v*a_src[hh*C+c]; d += v*a_dst[hh*C+c]; }
    al_s[(size_t)n*H+hh]=s; al_d[(size_t)n*H+hh]=d;
}

// ---------------- CSR build (once per call, reused by all 4 GAT layers) ----------------

__global__ __launch_bounds__(256) void k_deg(const int* __restrict__ ei, int E,
        int* __restrict__ deg){
    int e = blockIdx.x*256 + threadIdx.x;
    if (e < E) atomicAdd(deg + ei[E+e], 1);
}

__device__ __forceinline__ int wave_scan(int v, int lane){
    #pragma unroll
    for (int off=1; off<64; off<<=1){
        int t = __shfl_up(v, off, 64);
        if (lane >= off) v += t;
    }
    return v;
}

__global__ __launch_bounds__(1024) void k_scan1(const int* __restrict__ deg,
        int* __restrict__ excl, int* __restrict__ bsum, int N){
    __shared__ int ws[16];
    int i = blockIdx.x*1024 + threadIdx.x;
    int lane = threadIdx.x & 63, wid = threadIdx.x >> 6;
    int v = (i < N) ? deg[i] : 0;
    int inc = wave_scan(v, lane);
    if (lane == 63) ws[wid] = inc;
    __syncthreads();
    if (wid == 0){
        int wv = (lane < 16) ? ws[lane] : 0;
        int winc = wave_scan(wv, lane);
        if (lane < 16) ws[lane] = winc - wv;
    }
    __syncthreads();
    int off = ws[wid];
    if (i < N) excl[i] = off + inc - v;
    if (threadIdx.x == 1023) bsum[blockIdx.x] = off + inc;
}

__global__ void k_scan2(int* __restrict__ bsum, int nb){
    if (threadIdx.x == 0 && blockIdx.x == 0){
        int c = 0;
        for (int i = 0; i < nb; i++){ int t = bsum[i]; bsum[i] = c; c += t; }
    }
}

__global__ __launch_bounds__(256) void k_scan3(const int* __restrict__ excl,
        const int* __restrict__ bsum, int* __restrict__ rowptr,
        int* __restrict__ cursor, int N, int E){
    int i = blockIdx.x*256 + threadIdx.x;
    if (i < N){
        int r = excl[i] + bsum[i >> 10];
        rowptr[i] = r; cursor[i] = r;
    } else if (i == N){
        rowptr[N] = E;
    }
}

__global__ __launch_bounds__(256) void k_bucket(const int* __restrict__ ei, int E,
        int* __restrict__ cursor, int* __restrict__ csr){
    int e = blockIdx.x*256 + threadIdx.x;
    if (e >= E) return;
    int pos = atomicAdd(cursor + ei[E+e], 1);
    csr[pos] = ei[e];
}

// ---------------- GAT aggregation: one wave per dst, online softmax in registers ----------------

template<int H, int C>
__global__ __launch_bounds__(256) void k_gat_agg(
        const int* __restrict__ rowptr, const int* __restrict__ csr_src,
        const float* __restrict__ al_s, const float* __restrict__ al_d,
        const float* __restrict__ hfeat, const float* __restrict__ b,
        float* __restrict__ z, int N)
{
    constexpr int M = H*C;
    constexpr int EL = M/64;
    int dst = (blockIdx.x*blockDim.x + threadIdx.x) >> 6;
    if (dst >= N) return;
    int lane = threadIdx.x & 63;
    int j = EL*lane;
    int h = j / C;
    float ald = al_d[(size_t)dst*H + h];

    float v0 = al_s[(size_t)dst*H + h] + ald;
    v0 = v0 > 0.f ? v0 : LEAKY*v0;
    float m = v0, s = 1.f;
    float acc0, acc1 = 0.f;
    if (EL == 2){
        float2 hv = *(const float2*)(hfeat + (size_t)dst*M + j);
        acc0 = hv.x; acc1 = hv.y;
    } else {
        acc0 = hfeat[(size_t)dst*M + j];
    }

    int p1 = rowptr[dst+1];
    for (int p = rowptr[dst]; p < p1; ++p){
        int src = csr_src[p];
        float vv = al_s[(size_t)src*H + h] + ald;
        vv = vv > 0.f ? vv : LEAKY*vv;
        float mx = fmaxf(m, vv);
        float sc = __expf(m - mx);
        float ex = __expf(vv - mx);
        m = mx;
        s = s*sc + ex;
        if (EL == 2){
            float2 hv = *(const float2*)(hfeat + (size_t)src*M + j);
            acc0 = acc0*sc + hv.x*ex;
            acc1 = acc1*sc + hv.y*ex;
        } else {
            acc0 = acc0*sc + hfeat[(size_t)src*M + j]*ex;
        }
    }
    float inv = 1.f/(s + 1e-16f);
    if (EL == 2){
        z[(size_t)dst*M + j]     = acc0*inv + b[j];
        z[(size_t)dst*M + j + 1] = acc1*inv + b[j+1];
    } else {
        z[(size_t)dst*M + j] = acc0*inv + b[j];
    }
}

// ---------------- BN ----------------

__global__ void k_bn_stats(const float* __restrict__ z,
        float* __restrict__ cs, float* __restrict__ cq, int N){
    int j = threadIdx.x;                     // blockDim.x == 128
    float ls = 0.f, lq = 0.f;
    for (int n = blockIdx.x; n < N; n += gridDim.x){
        float v = z[(size_t)n*128 + j]; ls += v; lq += v*v;
    }
    atomicAdd(cs + j, ls); atomicAdd(cq + j, lq);
}

__global__ __launch_bounds__(256) void k_bn_relu(float* __restrict__ z,
        const float* __restrict__ gamma, const float* __restrict__ beta,
        const float* __restrict__ cs, const float* __restrict__ cq, int N){
    int gid = blockIdx.x*256 + threadIdx.x;
    int n = gid >> 7, j = gid & 127;
    if (n >= N) return;
    float invN = 1.f / (float)N;
    float mu = cs[j]*invN;
    float var = cq[j]*invN - mu*mu;
    float v = gamma[j]*(z[(size_t)n*128+j]-mu)*rsqrtf(var+BN_EPS)+beta[j];
    z[(size_t)n*128+j] = v > 0.f ? v : 0.f;
}

__global__ __launch_bounds__(256) void k_decoder(const float* __restrict__ z,
        const float* __restrict__ W, const float* __restrict__ b,
        float* __restrict__ out, int N){
    int gid = blockIdx.x*256 + threadIdx.x;
    int n = gid >> 2, o = gid & 3;
    if (n >= N) return;
    float acc = b[o];
    #pragma unroll
    for (int k=0;k<64;k++) acc += z[(size_t)n*64+k]*W[k*4+o];
    out[(size_t)n*4+o] = acc;
}

extern "C" void kernel_launch(void* const* d_in, const int* in_sizes, int n_in,
                              void* d_out, int out_size, void* d_ws, size_t ws_size,
                              hipStream_t stream){
    const float* x      = (const float*)d_in[0];
    const int*   ei     = (const int*)  d_in[1];
    const float* enc_W  = (const float*)d_in[2];
    const float* enc_b  = (const float*)d_in[3];
    const float* in_W   = (const float*)d_in[4];
    const float* in_as  = (const float*)d_in[5];
    const float* in_ad  = (const float*)d_in[6];
    const float* in_b   = (const float*)d_in[7];
    const float* hid_W  = (const float*)d_in[8];
    const float* hid_as = (const float*)d_in[9];
    const float* hid_ad = (const float*)d_in[10];
    const float* hid_b  = (const float*)d_in[11];
    const float* bn_g   = (const float*)d_in[12];
    const float* bn_b   = (const float*)d_in[13];
    const float* out_W  = (const float*)d_in[14];
    const float* out_as = (const float*)d_in[15];
    const float* out_ad = (const float*)d_in[16];
    const float* out_b  = (const float*)d_in[17];
    const float* dec_W  = (const float*)d_in[18];
    const float* dec_b  = (const float*)d_in[19];

    const int N = in_sizes[0] / 7;
    const int E = in_sizes[1] / 2;
    const int NB = (N + 1023) / 1024;
    const int NT = (N + 63) / 64;              // GEMM row tiles

    // workspace layout (fp32 / int32 / u16):
    float*    bufZ   = (float*)d_ws;                  // [N,128]
    float*    bufH   = bufZ + (size_t)N*128;          // [N,128]
    float*    al_s   = bufH + (size_t)N*128;          // [N,4]
    float*    al_d   = al_s + (size_t)N*4;            // [N,4]
    float*    cs     = al_d + (size_t)N*4;            // [128]
    float*    cq     = cs + 128;                      // [128]
    int*      deg    = (int*)(cq + 128);              // [N]
    int*      excl   = deg + N;                       // [N]
    int*      rowptr = excl + N;                      // [N+1]
    int*      cursor = rowptr + (N+1);                // [N]
    int*      bsum   = cursor + N;                    // [NB]
    int*      csr    = bsum + NB;                     // [E]
    u16*      wk     = (u16*)(((uintptr_t)(csr + E) + 15) & ~(uintptr_t)15);
    u16* wk_in_hi  = wk;                    u16* wk_in_lo  = wk_in_hi  + 64*128;
    u16* wk_h0_hi  = wk_in_lo  + 64*128;    u16* wk_h0_lo  = wk_h0_hi  + 128*128;
    u16* wk_h1_hi  = wk_h0_lo  + 128*128;   u16* wk_h1_lo  = wk_h1_hi  + 128*128;
    u16* wk_out_hi = wk_h1_lo  + 128*128;   u16* wk_out_lo = wk_out_hi + 128*64;

    // ---- pack weights (hi/lo bf16 fragments, once per call) ----
    k_pack_w<64,128><<<(64*128+255)/256, 256, 0, stream>>>(in_W, wk_in_hi, wk_in_lo);
    k_pack_w<128,128><<<(128*128+255)/256, 256, 0, stream>>>(hid_W, wk_h0_hi, wk_h0_lo);
    k_pack_w<128,128><<<(128*128+255)/256, 256, 0, stream>>>(hid_W + 128*128, wk_h1_hi, wk_h1_lo);
    k_pack_w<128,64><<<(128*64+255)/256, 256, 0, stream>>>(out_W, wk_out_hi, wk_out_lo);

    // ---- CSR build (by dst; self-loops handled inline in k_gat_agg) ----
    hipMemsetAsync(deg, 0, (size_t)N*sizeof(int), stream);
    k_deg   <<<(E+255)/256, 256, 0, stream>>>(ei, E, deg);
    k_scan1 <<<NB, 1024, 0, stream>>>(deg, excl, bsum, N);
    k_scan2 <<<1, 64, 0, stream>>>(bsum, NB);
    k_scan3 <<<(N+1+255)/256, 256, 0, stream>>>(excl, bsum, rowptr, cursor, N, E);
    k_bucket<<<(E+255)/256, 256, 0, stream>>>(ei, E, cursor, csr);

    // ---- encoder ----
    k_encoder<<<(N*64+255)/256, 256, 0, stream>>>(x, enc_W, enc_b, bufZ, N);

    // ---- GAT layer 1: K=64 -> 4x32, BN idx 0 ----
    k_gemm<64,128,2,2,2,4><<<NT, 256, 0, stream>>>(bufZ, wk_in_hi, wk_in_lo, bufH, N);
    k_att<4,32><<<(N*4+255)/256, 256, 0, stream>>>(bufH, in_as, in_ad, al_s, al_d, N);
    k_gat_agg<4,32><<<((size_t)N*64+255)/256, 256, 0, stream>>>(rowptr, csr, al_s, al_d, bufH, in_b, bufZ, N);
    hipMemsetAsync(cs, 0, 256*sizeof(float), stream);
    k_bn_stats<<<1024, 128, 0, stream>>>(bufZ, cs, cq, N);
    k_bn_relu<<<((size_t)N*128+255)/256, 256, 0, stream>>>(bufZ, bn_g, bn_b, cs, cq, N);

    // ---- hidden GAT layers ----
    for (int i = 0; i < 2; i++){
        const u16* whi = i ? wk_h1_hi : wk_h0_hi;
        const u16* wlo = i ? wk_h1_lo : wk_h0_lo;
        const float* as = hid_as + (size_t)i*128;
        const float* ad = hid_ad + (size_t)i*128;
        const float* bb = hid_b  + (size_t)i*128;
        k_gemm<128,128,2,2,2,4><<<NT, 256, 0, stream>>>(bufZ, whi, wlo, bufH, N);
        k_att<4,32><<<(N*4+255)/256, 256, 0, stream>>>(bufH, as, ad, al_s, al_d, N);
        k_gat_agg<4,32><<<((size_t)N*64+255)/256, 256, 0, stream>>>(rowptr, csr, al_s, al_d, bufH, bb, bufZ, N);
        hipMemsetAsync(cs, 0, 256*sizeof(float), stream);
        k_bn_stats<<<1024, 128, 0, stream>>>(bufZ, cs, cq, N);
        k_bn_relu<<<((size_t)N*128+255)/256, 256, 0, stream>>>(bufZ, bn_g + (i+1)*128, bn_b + (i+1)*128, cs, cq, N);
    }

    // ---- out GAT layer: K=128 -> 1x64 (concat=False, 1 head) ----
    k_gemm<128,64,4,1,1,4><<<NT, 256, 0, stream>>>(bufZ, wk_out_hi, wk_out_lo, bufH, N);
    k_att<1,64><<<(N+255)/256, 256, 0, stream>>>(bufH, out_as, out_ad, al_s, al_d, N);
    k_gat_agg<1,64><<<((size_t)N*64+255)/256, 256, 0, stream>>>(rowptr, csr, al_s, al_d, bufH, out_b, bufZ, N);

    // ---- decoder ----
    k_decoder<<<((size_t)N*4+255)/256, 256, 0, stream>>>(bufZ, dec_W, dec_b, (float*)d_out, N);
}

// Round 5
// 1110.617 us; speedup vs baseline: 4.4940x; 1.2179x over previous
//
#include <hip/hip_runtime.h>
#include <math.h>

#define LEAKY 0.2f
#define BN_EPS 1e-5f

typedef unsigned short u16;
typedef __bf16 bf16x8 __attribute__((ext_vector_type(8)));
typedef float f32x4 __attribute__((ext_vector_type(4)));
typedef u16 ushort8 __attribute__((ext_vector_type(8)));

__device__ __forceinline__ u16 f2bf(float x){
    unsigned u = __float_as_uint(x);
    u += 0x7FFFu + ((u >> 16) & 1u);          // RNE (finite data, no NaN)
    return (u16)(u >> 16);
}
__device__ __forceinline__ float bf2f(u16 b){ return __uint_as_float(((unsigned)b) << 16); }

// ---------------- encoder ----------------

__global__ __launch_bounds__(256) void k_encoder(const float* __restrict__ x,
        const float* __restrict__ W, const float* __restrict__ b,
        float* __restrict__ z, int N){
    int gid = blockIdx.x*256 + threadIdx.x;
    int n = gid >> 6, j = gid & 63;
    if (n >= N) return;
    float acc = b[j];
    #pragma unroll
    for (int k=0;k<7;k++) acc += x[n*7+k]*W[k*64+j];
    z[(size_t)n*64+j] = acc;
}

// pack W[K][M] fp32 -> hi/lo bf16 in MFMA B-fragment layout
template<int K, int M>
__global__ __launch_bounds__(256) void k_pack_w(const float* __restrict__ W,
        u16* __restrict__ hi, u16* __restrict__ lo){
    int idx = blockIdx.x*256 + threadIdx.x;
    if (idx >= K*M) return;
    int e = idx & 7, l16 = (idx >> 3) & 3, rest = idx >> 5;
    int n = rest % M, t = rest / M;
    int k = t*32 + l16*8 + e;
    float w = W[(size_t)k*M + n];
    u16 hb = f2bf(w);
    hi[idx] = hb;
    lo[idx] = f2bf(w - bf2f(hb));
}

// BN coefs: scale = gamma*rsqrt(var+eps); shift = beta - mu*scale
__global__ void k_bn_coef(const float* __restrict__ cs, const float* __restrict__ cq,
        const float* __restrict__ g, const float* __restrict__ be,
        float* __restrict__ scale, float* __restrict__ shift, float invN){
    int j = threadIdx.x;   // 128
    float mu = cs[j]*invN;
    float var = cq[j]*invN - mu*mu;
    float s = g[j]*rsqrtf(var + BN_EPS);
    scale[j] = s; shift[j] = be[j] - mu*s;
}

// split-bf16 MFMA GEMM, optional fused input-BN+ReLU (staging) and fused
// attention-logit epilogue; writes h as bf16.
template<int K, int M, int RW, int CW, int WR, int WC, int H, bool BNIN>
__global__ __launch_bounds__(256) void k_gemm(const float* __restrict__ z,
        const u16* __restrict__ Whi, const u16* __restrict__ Wlo,
        const float* __restrict__ bnscale, const float* __restrict__ bnshift,
        const float* __restrict__ a_src, const float* __restrict__ a_dst,
        u16* __restrict__ hout, float* __restrict__ al_s, float* __restrict__ al_d,
        int N)
{
    static_assert(RW*CW == 4 && RW*WR*16 == 64 && CW*WC*16 == M, "tile config");
    constexpr int KS = K/32;
    constexpr int KG = K/8;
    __shared__ __align__(16) u16 Ahi[64*K];
    __shared__ __align__(16) u16 Alo[64*K];
    const int brow = blockIdx.x*64;
    const int tid = threadIdx.x;

    // stage A-tile: fp32 -> (BN+ReLU) -> hi/lo bf16 fragments
    for (int u = tid; u < 64*KG; u += 256){
        int row = u / KG, kg = u % KG;
        int gr = brow + row;
        float v[8];
        if (gr < N){
            const float4* p = (const float4*)(z + (size_t)gr*K + kg*8);
            float4 a = p[0], bq = p[1];
            v[0]=a.x; v[1]=a.y; v[2]=a.z; v[3]=a.w;
            v[4]=bq.x; v[5]=bq.y; v[6]=bq.z; v[7]=bq.w;
            if (BNIN){
                const float4* sc = (const float4*)(bnscale + kg*8);
                const float4* sh = (const float4*)(bnshift + kg*8);
                float4 s0=sc[0], s1=sc[1], t0=sh[0], t1=sh[1];
                v[0]=fmaxf(fmaf(v[0],s0.x,t0.x),0.f);
                v[1]=fmaxf(fmaf(v[1],s0.y,t0.y),0.f);
                v[2]=fmaxf(fmaf(v[2],s0.z,t0.z),0.f);
                v[3]=fmaxf(fmaf(v[3],s0.w,t0.w),0.f);
                v[4]=fmaxf(fmaf(v[4],s1.x,t1.x),0.f);
                v[5]=fmaxf(fmaf(v[5],s1.y,t1.y),0.f);
                v[6]=fmaxf(fmaf(v[6],s1.z,t1.z),0.f);
                v[7]=fmaxf(fmaf(v[7],s1.w,t1.w),0.f);
            }
        } else {
            #pragma unroll
            for (int e=0;e<8;e++) v[e]=0.f;
        }
        ushort8 h8, l8;
        #pragma unroll
        for (int e=0;e<8;e++){
            u16 hb = f2bf(v[e]);
            h8[e] = hb;
            l8[e] = f2bf(v[e] - bf2f(hb));
        }
        int rb = row >> 4, t = kg >> 2, lg = kg & 3;
        int base = (((rb*KS + t)*64) + (row & 15) + 16*lg)*8;
        *(ushort8*)&Ahi[base] = h8;
        *(ushort8*)&Alo[base] = l8;
    }
    __syncthreads();

    const int wave = tid >> 6, lane = tid & 63;
    const int wrow = wave / CW, wcol = wave % CW;
    const int l15 = lane & 15, l16 = lane >> 4;

    f32x4 acc[WR][WC];
    #pragma unroll
    for (int r=0;r<WR;r++)
        #pragma unroll
        for (int c=0;c<WC;c++) acc[r][c] = (f32x4){0.f,0.f,0.f,0.f};

    #pragma unroll
    for (int t = 0; t < KS; ++t){
        bf16x8 ah[WR], al[WR];
        #pragma unroll
        for (int r=0;r<WR;r++){
            int rb = wrow*WR + r;
            int off = ((rb*KS + t)*64 + lane)*8;
            ah[r] = *(const bf16x8*)&Ahi[off];
            al[r] = *(const bf16x8*)&Alo[off];
        }
        bf16x8 bh[WC], bl[WC];
        #pragma unroll
        for (int c=0;c<WC;c++){
            int n = (wcol*WC + c)*16 + l15;
            size_t off = ((size_t)(t*M + n)*4 + (size_t)l16)*8;
            bh[c] = *(const bf16x8*)&Whi[off];
            bl[c] = *(const bf16x8*)&Wlo[off];
        }
        #pragma unroll
        for (int r=0;r<WR;r++)
            #pragma unroll
            for (int c=0;c<WC;c++){
                acc[r][c] = __builtin_amdgcn_mfma_f32_16x16x32_bf16(al[r], bh[c], acc[r][c], 0,0,0);
                acc[r][c] = __builtin_amdgcn_mfma_f32_16x16x32_bf16(ah[r], bl[c], acc[r][c], 0,0,0);
                acc[r][c] = __builtin_amdgcn_mfma_f32_16x16x32_bf16(ah[r], bh[c], acc[r][c], 0,0,0);
            }
    }

    // fused attention-logit epilogue: heads partition across waves/frag-pairs
    float as_[WC], ad_[WC];
    #pragma unroll
    for (int c=0;c<WC;c++){
        int colg = (wcol*WC + c)*16 + l15;
        as_[c] = a_src[colg]; ad_[c] = a_dst[colg];
    }
    #pragma unroll
    for (int r=0;r<WR;r++){
        #pragma unroll
        for (int q=0;q<4;q++){
            int rowg = brow + (wrow*WR + r)*16 + l16*4 + q;
            float s0=0.f,d0=0.f,s1=0.f,d1=0.f;
            #pragma unroll
            for (int c=0;c<WC;c++){
                float av = acc[r][c][q];
                if (H==1 || c < WC/2){ s0 += av*as_[c]; d0 += av*ad_[c]; }
                else                 { s1 += av*as_[c]; d1 += av*ad_[c]; }
            }
            #pragma unroll
            for (int off=1; off<16; off<<=1){
                s0 += __shfl_xor(s0, off, 64); d0 += __shfl_xor(d0, off, 64);
                if (H==4){ s1 += __shfl_xor(s1, off, 64); d1 += __shfl_xor(d1, off, 64); }
            }
            if (l15 == 0 && rowg < N){
                if (H==4){
                    al_s[(size_t)rowg*4 + wcol*2]     = s0;
                    al_s[(size_t)rowg*4 + wcol*2 + 1] = s1;
                    al_d[(size_t)rowg*4 + wcol*2]     = d0;
                    al_d[(size_t)rowg*4 + wcol*2 + 1] = d1;
                } else {
                    al_s[rowg] = s0; al_d[rowg] = d0;
                }
            }
        }
    }

    // h write (bf16)
    #pragma unroll
    for (int r=0;r<WR;r++)
        #pragma unroll
        for (int c=0;c<WC;c++){
            int colg = (wcol*WC + c)*16 + l15;
            #pragma unroll
            for (int q=0;q<4;q++){
                int rowg = brow + (wrow*WR + r)*16 + l16*4 + q;
                if (rowg < N) hout[(size_t)rowg*M + colg] = f2bf(acc[r][c][q]);
            }
        }
}

// ---------------- CSR build (once per call) ----------------

__global__ __launch_bounds__(256) void k_deg(const int* __restrict__ ei, int E,
        int* __restrict__ deg){
    int e = blockIdx.x*256 + threadIdx.x;
    if (e < E) atomicAdd(deg + ei[E+e], 1);
}

__device__ __forceinline__ int wave_scan(int v, int lane){
    #pragma unroll
    for (int off=1; off<64; off<<=1){
        int t = __shfl_up(v, off, 64);
        if (lane >= off) v += t;
    }
    return v;
}

__global__ __launch_bounds__(1024) void k_scan1(const int* __restrict__ deg,
        int* __restrict__ excl, int* __restrict__ bsum, int N){
    __shared__ int ws[16];
    int i = blockIdx.x*1024 + threadIdx.x;
    int lane = threadIdx.x & 63, wid = threadIdx.x >> 6;
    int v = (i < N) ? deg[i] : 0;
    int inc = wave_scan(v, lane);
    if (lane == 63) ws[wid] = inc;
    __syncthreads();
    if (wid == 0){
        int wv = (lane < 16) ? ws[lane] : 0;
        int winc = wave_scan(wv, lane);
        if (lane < 16) ws[lane] = winc - wv;
    }
    __syncthreads();
    int off = ws[wid];
    if (i < N) excl[i] = off + inc - v;
    if (threadIdx.x == 1023) bsum[blockIdx.x] = off + inc;
}

__global__ void k_scan2(int* __restrict__ bsum, int nb){
    if (threadIdx.x == 0 && blockIdx.x == 0){
        int c = 0;
        for (int i = 0; i < nb; i++){ int t = bsum[i]; bsum[i] = c; c += t; }
    }
}

__global__ __launch_bounds__(256) void k_scan3(const int* __restrict__ excl,
        const int* __restrict__ bsum, int* __restrict__ rowptr,
        int* __restrict__ cursor, int N, int E){
    int i = blockIdx.x*256 + threadIdx.x;
    if (i < N){
        int r = excl[i] + bsum[i >> 10];
        rowptr[i] = r; cursor[i] = r;
    } else if (i == N){
        rowptr[N] = E;
    }
}

__global__ __launch_bounds__(256) void k_bucket(const int* __restrict__ ei, int E,
        int* __restrict__ cursor, int* __restrict__ csr){
    int e = blockIdx.x*256 + threadIdx.x;
    if (e >= E) return;
    int pos = atomicAdd(cursor + ei[E+e], 1);
    csr[pos] = ei[e];
}

// ---------------- GAT aggregation: wave per dst (grid-stride), bf16 gathers,
// online softmax, fused BN stats and optional fused decoder ----------------

template<int H, int C, bool STATS, bool DECODE>
__global__ __launch_bounds__(256) void k_gat_agg(
        const int* __restrict__ rowptr, const int* __restrict__ csr_src,
        const float* __restrict__ al_s, const float* __restrict__ al_d,
        const u16* __restrict__ hfeat, const float* __restrict__ b,
        float* __restrict__ z, float* __restrict__ cs, float* __restrict__ cq,
        const float* __restrict__ decW, const float* __restrict__ decb,
        float* __restrict__ out, int N, int totWaves)
{
    constexpr int M = H*C;
    constexpr int EL = M/64;                  // 2 (M=128) or 1 (M=64)
    const int lane = threadIdx.x & 63;
    const int j = EL*lane;
    const int h = j / C;
    const int gw = blockIdx.x*4 + (threadIdx.x >> 6);

    const float bj0 = b[j];
    const float bj1 = (EL==2) ? b[j+1] : 0.f;
    float w0=0,w1=0,w2=0,w3=0;
    if (DECODE){ w0=decW[lane*4]; w1=decW[lane*4+1]; w2=decW[lane*4+2]; w3=decW[lane*4+3]; }
    float ls0=0.f, ls1=0.f, lq0=0.f, lq1=0.f;

    for (int dst = gw; dst < N; dst += totWaves){
        float ald = al_d[(size_t)dst*H + h];
        float v0 = al_s[(size_t)dst*H + h] + ald;
        v0 = v0 > 0.f ? v0 : LEAKY*v0;
        float m = v0, s = 1.f;
        float acc0, acc1 = 0.f;
        if (EL==2){
            unsigned hv = *(const unsigned*)(hfeat + (size_t)dst*M + j);
            acc0 = bf2f((u16)hv); acc1 = bf2f((u16)(hv>>16));
        } else {
            acc0 = bf2f(hfeat[(size_t)dst*M + j]);
        }
        int p0 = rowptr[dst], p1 = rowptr[dst+1];
        unsigned hvc=0; float vsc=0.f;
        if (p0 < p1){
            int s0i = csr_src[p0];
            vsc = al_s[(size_t)s0i*H + h];
            if (EL==2) hvc = *(const unsigned*)(hfeat + (size_t)s0i*M + j);
            else       hvc = hfeat[(size_t)s0i*M + j];
        }
        for (int p = p0; p < p1; ++p){
            unsigned hvn=0; float vsn=0.f;
            if (p+1 < p1){
                int sn = csr_src[p+1];
                vsn = al_s[(size_t)sn*H + h];
                if (EL==2) hvn = *(const unsigned*)(hfeat + (size_t)sn*M + j);
                else       hvn = hfeat[(size_t)sn*M + j];
            }
            float vv = vsc + ald;
            vv = vv > 0.f ? vv : LEAKY*vv;
            float mx = fmaxf(m, vv);
            float sc = __expf(m - mx);
            float ex = __expf(vv - mx);
            m = mx; s = s*sc + ex;
            acc0 = acc0*sc + bf2f((u16)hvc)*ex;
            if (EL==2) acc1 = acc1*sc + bf2f((u16)(hvc>>16))*ex;
            hvc = hvn; vsc = vsn;
        }
        float inv = 1.f/(s + 1e-16f);
        float o0 = acc0*inv + bj0;
        float o1 = (EL==2) ? acc1*inv + bj1 : 0.f;
        if (STATS){ ls0+=o0; lq0+=o0*o0; ls1+=o1; lq1+=o1*o1; }
        if (!DECODE){
            if (EL==2) *(float2*)(z + (size_t)dst*M + j) = make_float2(o0,o1);
            else       z[(size_t)dst*M + j] = o0;
        } else {
            float a0=o0*w0, a1=o0*w1, a2=o0*w2, a3=o0*w3;
            #pragma unroll
            for (int off=32; off; off>>=1){
                a0 += __shfl_xor(a0, off, 64);
                a1 += __shfl_xor(a1, off, 64);
                a2 += __shfl_xor(a2, off, 64);
                a3 += __shfl_xor(a3, off, 64);
            }
            if (lane == 0){
                float4 o = make_float4(a0+decb[0], a1+decb[1], a2+decb[2], a3+decb[3]);
                *(float4*)(out + (size_t)dst*4) = o;
            }
        }
    }
    if (STATS){
        __shared__ float sls[128], slq[128];
        if (threadIdx.x < 128){ sls[threadIdx.x]=0.f; slq[threadIdx.x]=0.f; }
        __syncthreads();
        atomicAdd(&sls[j], ls0);  atomicAdd(&slq[j], lq0);
        if (EL==2){ atomicAdd(&sls[j+1], ls1); atomicAdd(&slq[j+1], lq1); }
        __syncthreads();
        if (threadIdx.x < 128){
            atomicAdd(cs + threadIdx.x, sls[threadIdx.x]);
            atomicAdd(cq + threadIdx.x, slq[threadIdx.x]);
        }
    }
}

extern "C" void kernel_launch(void* const* d_in, const int* in_sizes, int n_in,
                              void* d_out, int out_size, void* d_ws, size_t ws_size,
                              hipStream_t stream){
    const float* x      = (const float*)d_in[0];
    const int*   ei     = (const int*)  d_in[1];
    const float* enc_W  = (const float*)d_in[2];
    const float* enc_b  = (const float*)d_in[3];
    const float* in_W   = (const float*)d_in[4];
    const float* in_as  = (const float*)d_in[5];
    const float* in_ad  = (const float*)d_in[6];
    const float* in_b   = (const float*)d_in[7];
    const float* hid_W  = (const float*)d_in[8];
    const float* hid_as = (const float*)d_in[9];
    const float* hid_ad = (const float*)d_in[10];
    const float* hid_b  = (const float*)d_in[11];
    const float* bn_g   = (const float*)d_in[12];
    const float* bn_b   = (const float*)d_in[13];
    const float* out_W  = (const float*)d_in[14];
    const float* out_as = (const float*)d_in[15];
    const float* out_ad = (const float*)d_in[16];
    const float* out_b  = (const float*)d_in[17];
    const float* dec_W  = (const float*)d_in[18];
    const float* dec_b  = (const float*)d_in[19];

    const int N = in_sizes[0] / 7;
    const int E = in_sizes[1] / 2;
    const int NB = (N + 1023) / 1024;
    const int NT = (N + 63) / 64;
    const int AGG_BLOCKS = 2048, TOT_WAVES = AGG_BLOCKS*4;

    // workspace layout:
    float*    bufZ   = (float*)d_ws;                  // [N,128] fp32 activations
    float*    al_s   = bufZ + (size_t)N*128;          // [N,4]
    float*    al_d   = al_s + (size_t)N*4;            // [N,4]
    float*    cs     = al_d + (size_t)N*4;            // [128]
    float*    cq     = cs + 128;                      // [128]
    float*    scale  = cq + 128;                      // [128]
    float*    shift  = scale + 128;                   // [128]
    int*      deg    = (int*)(shift + 128);           // [N]
    int*      excl   = deg + N;                       // [N]
    int*      rowptr = excl + N;                      // [N+1]
    int*      cursor = rowptr + (N+1);                // [N]
    int*      bsum   = cursor + N;                    // [NB]
    int*      csr    = bsum + NB;                     // [E]
    u16*      hb     = (u16*)(((uintptr_t)(csr + E) + 15) & ~(uintptr_t)15); // [N,128] bf16
    u16*      wk     = hb + (size_t)N*128;
    u16* wk_in_hi  = wk;                    u16* wk_in_lo  = wk_in_hi  + 64*128;
    u16* wk_h0_hi  = wk_in_lo  + 64*128;    u16* wk_h0_lo  = wk_h0_hi  + 128*128;
    u16* wk_h1_hi  = wk_h0_lo  + 128*128;   u16* wk_h1_lo  = wk_h1_hi  + 128*128;
    u16* wk_out_hi = wk_h1_lo  + 128*128;   u16* wk_out_lo = wk_out_hi + 128*64;

    // ---- pack weights ----
    k_pack_w<64,128><<<(64*128+255)/256, 256, 0, stream>>>(in_W, wk_in_hi, wk_in_lo);
    k_pack_w<128,128><<<(128*128+255)/256, 256, 0, stream>>>(hid_W, wk_h0_hi, wk_h0_lo);
    k_pack_w<128,128><<<(128*128+255)/256, 256, 0, stream>>>(hid_W + 128*128, wk_h1_hi, wk_h1_lo);
    k_pack_w<128,64><<<(128*64+255)/256, 256, 0, stream>>>(out_W, wk_out_hi, wk_out_lo);

    // ---- CSR build ----
    hipMemsetAsync(deg, 0, (size_t)N*sizeof(int), stream);
    k_deg   <<<(E+255)/256, 256, 0, stream>>>(ei, E, deg);
    k_scan1 <<<NB, 1024, 0, stream>>>(deg, excl, bsum, N);
    k_scan2 <<<1, 64, 0, stream>>>(bsum, NB);
    k_scan3 <<<(N+1+255)/256, 256, 0, stream>>>(excl, bsum, rowptr, cursor, N, E);
    k_bucket<<<(E+255)/256, 256, 0, stream>>>(ei, E, cursor, csr);

    // ---- encoder ----
    k_encoder<<<(N*64+255)/256, 256, 0, stream>>>(x, enc_W, enc_b, bufZ, N);

    const float invN = 1.f/(float)N;

    // ---- GAT layer 1 (K=64, no input BN) ----
    k_gemm<64,128,2,2,2,4,4,false><<<NT, 256, 0, stream>>>(bufZ, wk_in_hi, wk_in_lo,
            nullptr, nullptr, in_as, in_ad, hb, al_s, al_d, N);
    hipMemsetAsync(cs, 0, 256*sizeof(float), stream);
    k_gat_agg<4,32,true,false><<<AGG_BLOCKS, 256, 0, stream>>>(rowptr, csr, al_s, al_d,
            hb, in_b, bufZ, cs, cq, nullptr, nullptr, nullptr, N, TOT_WAVES);
    k_bn_coef<<<1, 128, 0, stream>>>(cs, cq, bn_g, bn_b, scale, shift, invN);

    // ---- hidden GAT layers (input BN+ReLU fused into GEMM staging) ----
    for (int i = 0; i < 2; i++){
        const u16* whi = i ? wk_h1_hi : wk_h0_hi;
        const u16* wlo = i ? wk_h1_lo : wk_h0_lo;
        k_gemm<128,128,2,2,2,4,4,true><<<NT, 256, 0, stream>>>(bufZ, whi, wlo,
                scale, shift, hid_as + (size_t)i*128, hid_ad + (size_t)i*128,
                hb, al_s, al_d, N);
        hipMemsetAsync(cs, 0, 256*sizeof(float), stream);
        k_gat_agg<4,32,true,false><<<AGG_BLOCKS, 256, 0, stream>>>(rowptr, csr, al_s, al_d,
                hb, hid_b + (size_t)i*128, bufZ, cs, cq, nullptr, nullptr, nullptr, N, TOT_WAVES);
        k_bn_coef<<<1, 128, 0, stream>>>(cs, cq, bn_g + (i+1)*128, bn_b + (i+1)*128, scale, shift, invN);
    }

    // ---- out GAT layer (K=128 -> 1x64) + fused decoder ----
    k_gemm<128,64,4,1,1,4,1,true><<<NT, 256, 0, stream>>>(bufZ, wk_out_hi, wk_out_lo,
            scale, shift, out_as, out_ad, hb, al_s, al_d, N);
    k_gat_agg<1,64,false,true><<<AGG_BLOCKS, 256, 0, stream>>>(rowptr, csr, al_s, al_d,
            hb, out_b, nullptr, nullptr, nullptr, dec_W, dec_b, (float*)d_out, N, TOT_WAVES);
}

// Round 6
// 966.793 us; speedup vs baseline: 5.1625x; 1.1488x over previous
//
#include <hip/hip_runtime.h>
#include <math.h>

#define LEAKY 0.2f
#define BN_EPS 1e-5f

typedef unsigned short u16;
typedef __bf16 bf16x8 __attribute__((ext_vector_type(8)));
typedef float f32x4 __attribute__((ext_vector_type(4)));
typedef u16 ushort8 __attribute__((ext_vector_type(8)));

__device__ __forceinline__ u16 f2bf(float x){
    unsigned u = __float_as_uint(x);
    u += 0x7FFFu + ((u >> 16) & 1u);          // RNE (finite data, no NaN)
    return (u16)(u >> 16);
}
__device__ __forceinline__ float bf2f(u16 b){ return __uint_as_float(((unsigned)b) << 16); }

// ---------------- encoder ----------------

__global__ __launch_bounds__(256) void k_encoder(const float* __restrict__ x,
        const float* __restrict__ W, const float* __restrict__ b,
        float* __restrict__ z, int N){
    int gid = blockIdx.x*256 + threadIdx.x;
    int n = gid >> 6, j = gid & 63;
    if (n >= N) return;
    float acc = b[j];
    #pragma unroll
    for (int k=0;k<7;k++) acc += x[n*7+k]*W[k*64+j];
    z[(size_t)n*64+j] = acc;
}

// pack W[K][M] fp32 -> hi/lo bf16 in MFMA B-fragment layout
template<int K, int M>
__global__ __launch_bounds__(256) void k_pack_w(const float* __restrict__ W,
        u16* __restrict__ hi, u16* __restrict__ lo){
    int idx = blockIdx.x*256 + threadIdx.x;
    if (idx >= K*M) return;
    int e = idx & 7, l16 = (idx >> 3) & 3, rest = idx >> 5;
    int n = rest % M, t = rest / M;
    int k = t*32 + l16*8 + e;
    float w = W[(size_t)k*M + n];
    u16 hb = f2bf(w);
    hi[idx] = hb;
    lo[idx] = f2bf(w - bf2f(hb));
}

// BN coefs: scale = gamma*rsqrt(var+eps); shift = beta - mu*scale
__global__ void k_bn_coef(const float* __restrict__ cs, const float* __restrict__ cq,
        const float* __restrict__ g, const float* __restrict__ be,
        float* __restrict__ scale, float* __restrict__ shift, float invN){
    int j = threadIdx.x;   // 128
    float mu = cs[j]*invN;
    float var = cq[j]*invN - mu*mu;
    float s = g[j]*rsqrtf(var + BN_EPS);
    scale[j] = s; shift[j] = be[j] - mu*s;
}

// split-bf16 MFMA GEMM, optional fused input-BN+ReLU (staging) and fused
// attention-logit epilogue; writes h as bf16.
template<int K, int M, int RW, int CW, int WR, int WC, int H, bool BNIN>
__global__ __launch_bounds__(256) void k_gemm(const float* __restrict__ z,
        const u16* __restrict__ Whi, const u16* __restrict__ Wlo,
        const float* __restrict__ bnscale, const float* __restrict__ bnshift,
        const float* __restrict__ a_src, const float* __restrict__ a_dst,
        u16* __restrict__ hout, float* __restrict__ al_s, float* __restrict__ al_d,
        int N)
{
    static_assert(RW*CW == 4 && RW*WR*16 == 64 && CW*WC*16 == M, "tile config");
    constexpr int KS = K/32;
    constexpr int KG = K/8;
    __shared__ __align__(16) u16 Ahi[64*K];
    __shared__ __align__(16) u16 Alo[64*K];
    const int brow = blockIdx.x*64;
    const int tid = threadIdx.x;

    // stage A-tile: fp32 -> (BN+ReLU) -> hi/lo bf16 fragments
    for (int u = tid; u < 64*KG; u += 256){
        int row = u / KG, kg = u % KG;
        int gr = brow + row;
        float v[8];
        if (gr < N){
            const float4* p = (const float4*)(z + (size_t)gr*K + kg*8);
            float4 a = p[0], bq = p[1];
            v[0]=a.x; v[1]=a.y; v[2]=a.z; v[3]=a.w;
            v[4]=bq.x; v[5]=bq.y; v[6]=bq.z; v[7]=bq.w;
            if (BNIN){
                const float4* sc = (const float4*)(bnscale + kg*8);
                const float4* sh = (const float4*)(bnshift + kg*8);
                float4 s0=sc[0], s1=sc[1], t0=sh[0], t1=sh[1];
                v[0]=fmaxf(fmaf(v[0],s0.x,t0.x),0.f);
                v[1]=fmaxf(fmaf(v[1],s0.y,t0.y),0.f);
                v[2]=fmaxf(fmaf(v[2],s0.z,t0.z),0.f);
                v[3]=fmaxf(fmaf(v[3],s0.w,t0.w),0.f);
                v[4]=fmaxf(fmaf(v[4],s1.x,t1.x),0.f);
                v[5]=fmaxf(fmaf(v[5],s1.y,t1.y),0.f);
                v[6]=fmaxf(fmaf(v[6],s1.z,t1.z),0.f);
                v[7]=fmaxf(fmaf(v[7],s1.w,t1.w),0.f);
            }
        } else {
            #pragma unroll
            for (int e=0;e<8;e++) v[e]=0.f;
        }
        ushort8 h8, l8;
        #pragma unroll
        for (int e=0;e<8;e++){
            u16 hb = f2bf(v[e]);
            h8[e] = hb;
            l8[e] = f2bf(v[e] - bf2f(hb));
        }
        int rb = row >> 4, t = kg >> 2, lg = kg & 3;
        int base = (((rb*KS + t)*64) + (row & 15) + 16*lg)*8;
        *(ushort8*)&Ahi[base] = h8;
        *(ushort8*)&Alo[base] = l8;
    }
    __syncthreads();

    const int wave = tid >> 6, lane = tid & 63;
    const int wrow = wave / CW, wcol = wave % CW;
    const int l15 = lane & 15, l16 = lane >> 4;

    f32x4 acc[WR][WC];
    #pragma unroll
    for (int r=0;r<WR;r++)
        #pragma unroll
        for (int c=0;c<WC;c++) acc[r][c] = (f32x4){0.f,0.f,0.f,0.f};

    #pragma unroll
    for (int t = 0; t < KS; ++t){
        bf16x8 ah[WR], al[WR];
        #pragma unroll
        for (int r=0;r<WR;r++){
            int rb = wrow*WR + r;
            int off = ((rb*KS + t)*64 + lane)*8;
            ah[r] = *(const bf16x8*)&Ahi[off];
            al[r] = *(const bf16x8*)&Alo[off];
        }
        bf16x8 bh[WC], bl[WC];
        #pragma unroll
        for (int c=0;c<WC;c++){
            int n = (wcol*WC + c)*16 + l15;
            size_t off = ((size_t)(t*M + n)*4 + (size_t)l16)*8;
            bh[c] = *(const bf16x8*)&Whi[off];
            bl[c] = *(const bf16x8*)&Wlo[off];
        }
        #pragma unroll
        for (int r=0;r<WR;r++)
            #pragma unroll
            for (int c=0;c<WC;c++){
                acc[r][c] = __builtin_amdgcn_mfma_f32_16x16x32_bf16(al[r], bh[c], acc[r][c], 0,0,0);
                acc[r][c] = __builtin_amdgcn_mfma_f32_16x16x32_bf16(ah[r], bl[c], acc[r][c], 0,0,0);
                acc[r][c] = __builtin_amdgcn_mfma_f32_16x16x32_bf16(ah[r], bh[c], acc[r][c], 0,0,0);
            }
    }

    // fused attention-logit epilogue
    float as_[WC], ad_[WC];
    #pragma unroll
    for (int c=0;c<WC;c++){
        int colg = (wcol*WC + c)*16 + l15;
        as_[c] = a_src[colg]; ad_[c] = a_dst[colg];
    }
    #pragma unroll
    for (int r=0;r<WR;r++){
        #pragma unroll
        for (int q=0;q<4;q++){
            int rowg = brow + (wrow*WR + r)*16 + l16*4 + q;
            float s0=0.f,d0=0.f,s1=0.f,d1=0.f;
            #pragma unroll
            for (int c=0;c<WC;c++){
                float av = acc[r][c][q];
                if (H==1 || c < WC/2){ s0 += av*as_[c]; d0 += av*ad_[c]; }
                else                 { s1 += av*as_[c]; d1 += av*ad_[c]; }
            }
            #pragma unroll
            for (int off=1; off<16; off<<=1){
                s0 += __shfl_xor(s0, off, 64); d0 += __shfl_xor(d0, off, 64);
                if (H==4){ s1 += __shfl_xor(s1, off, 64); d1 += __shfl_xor(d1, off, 64); }
            }
            if (l15 == 0 && rowg < N){
                if (H==4){
                    al_s[(size_t)rowg*4 + wcol*2]     = s0;
                    al_s[(size_t)rowg*4 + wcol*2 + 1] = s1;
                    al_d[(size_t)rowg*4 + wcol*2]     = d0;
                    al_d[(size_t)rowg*4 + wcol*2 + 1] = d1;
                } else {
                    al_s[rowg] = s0; al_d[rowg] = d0;
                }
            }
        }
    }

    // h write (bf16)
    #pragma unroll
    for (int r=0;r<WR;r++)
        #pragma unroll
        for (int c=0;c<WC;c++){
            int colg = (wcol*WC + c)*16 + l15;
            #pragma unroll
            for (int q=0;q<4;q++){
                int rowg = brow + (wrow*WR + r)*16 + l16*4 + q;
                if (rowg < N) hout[(size_t)rowg*M + colg] = f2bf(acc[r][c][q]);
            }
        }
}

// ---------------- CSR build (once per call) ----------------

__global__ __launch_bounds__(256) void k_deg(const int* __restrict__ ei, int E,
        int* __restrict__ deg){
    int e = blockIdx.x*256 + threadIdx.x;
    if (e < E) atomicAdd(deg + ei[E+e], 1);
}

__device__ __forceinline__ int wave_scan(int v, int lane){
    #pragma unroll
    for (int off=1; off<64; off<<=1){
        int t = __shfl_up(v, off, 64);
        if (lane >= off) v += t;
    }
    return v;
}

__global__ __launch_bounds__(1024) void k_scan1(const int* __restrict__ deg,
        int* __restrict__ excl, int* __restrict__ bsum, int N){
    __shared__ int ws[16];
    int i = blockIdx.x*1024 + threadIdx.x;
    int lane = threadIdx.x & 63, wid = threadIdx.x >> 6;
    int v = (i < N) ? deg[i] : 0;
    int inc = wave_scan(v, lane);
    if (lane == 63) ws[wid] = inc;
    __syncthreads();
    if (wid == 0){
        int wv = (lane < 16) ? ws[lane] : 0;
        int winc = wave_scan(wv, lane);
        if (lane < 16) ws[lane] = winc - wv;
    }
    __syncthreads();
    int off = ws[wid];
    if (i < N) excl[i] = off + inc - v;
    if (threadIdx.x == 1023) bsum[blockIdx.x] = off + inc;
}

__global__ void k_scan2(int* __restrict__ bsum, int nb){
    if (threadIdx.x == 0 && blockIdx.x == 0){
        int c = 0;
        for (int i = 0; i < nb; i++){ int t = bsum[i]; bsum[i] = c; c += t; }
    }
}

__global__ __launch_bounds__(256) void k_scan3(const int* __restrict__ excl,
        const int* __restrict__ bsum, int* __restrict__ rowptr,
        int* __restrict__ cursor, int N, int E){
    int i = blockIdx.x*256 + threadIdx.x;
    if (i < N){
        int r = excl[i] + bsum[i >> 10];
        rowptr[i] = r; cursor[i] = r;
    } else if (i == N){
        rowptr[N] = E;
    }
}

__global__ __launch_bounds__(256) void k_bucket(const int* __restrict__ ei, int E,
        int* __restrict__ cursor, int* __restrict__ csr){
    int e = blockIdx.x*256 + threadIdx.x;
    if (e >= E) return;
    int pos = atomicAdd(cursor + ei[E+e], 1);
    csr[pos] = ei[e];
}

// ---------------- GAT aggregation: wave per dst (grid-stride), bf16 gathers,
// online softmax, quad ping-pong prefetch (8 edges in flight), fused BN stats
// and optional fused decoder ----------------

template<int H, int C, bool STATS, bool DECODE>
__global__ __launch_bounds__(256) void k_gat_agg(
        const int* __restrict__ rowptr, const int* __restrict__ csr_src,
        const float* __restrict__ al_s, const float* __restrict__ al_d,
        const u16* __restrict__ hfeat, const float* __restrict__ b,
        float* __restrict__ z, float* __restrict__ cs, float* __restrict__ cq,
        const float* __restrict__ decW, const float* __restrict__ decb,
        float* __restrict__ out, int N, int totWaves)
{
    constexpr int M = H*C;
    constexpr int EL = M/64;                  // 2 (M=128) or 1 (M=64)
    const int lane = threadIdx.x & 63;
    const int j = EL*lane;
    const int h = j / C;
    const int gw = blockIdx.x*4 + (threadIdx.x >> 6);

    const float bj0 = b[j];
    const float bj1 = (EL==2) ? b[j+1] : 0.f;
    float w0=0,w1=0,w2=0,w3=0;
    if (DECODE){ w0=decW[lane*4]; w1=decW[lane*4+1]; w2=decW[lane*4+2]; w3=decW[lane*4+3]; }
    float ls0=0.f, ls1=0.f, lq0=0.f, lq1=0.f;

    for (int dst = gw; dst < N; dst += totWaves){
        int p0 = rowptr[dst], p1 = rowptr[dst+1];     // issue early
        float ald = al_d[(size_t)dst*H + h];
        float v0 = al_s[(size_t)dst*H + h] + ald;
        v0 = v0 > 0.f ? v0 : LEAKY*v0;
        float m = v0, s = 1.f;
        float acc0, acc1 = 0.f;
        if (EL==2){
            unsigned hv = *(const unsigned*)(hfeat + (size_t)dst*M + j);
            acc0 = bf2f((u16)hv); acc1 = bf2f((u16)(hv>>16));
        } else {
            acc0 = bf2f(hfeat[(size_t)dst*M + j]);
        }

        auto ld = [&](int idx, unsigned& hv, float& vs){
            if (idx < p1){
                int src = csr_src[idx];
                vs = al_s[(size_t)src*H + h];
                if (EL==2) hv = *(const unsigned*)(hfeat + (size_t)src*M + j);
                else       hv = (unsigned)hfeat[(size_t)src*M + j];
            }
        };
        auto proc = [&](unsigned hv, float vs){
            float vv = vs + ald;
            vv = vv > 0.f ? vv : LEAKY*vv;
            float mx = fmaxf(m, vv);
            float sc = __expf(m - mx);
            float ex = __expf(vv - mx);
            m = mx; s = s*sc + ex;
            acc0 = acc0*sc + bf2f((u16)hv)*ex;
            if (EL==2) acc1 = acc1*sc + bf2f((u16)(hv>>16))*ex;
        };

        unsigned hA0=0,hA1=0,hA2=0,hA3=0, hB0=0,hB1=0,hB2=0,hB3=0;
        float vA0=0,vA1=0,vA2=0,vA3=0, vB0=0,vB1=0,vB2=0,vB3=0;
        int p = p0;
        ld(p, hA0, vA0); ld(p+1, hA1, vA1); ld(p+2, hA2, vA2); ld(p+3, hA3, vA3);
        while (p < p1){
            ld(p+4, hB0, vB0); ld(p+5, hB1, vB1); ld(p+6, hB2, vB2); ld(p+7, hB3, vB3);
            proc(hA0, vA0);
            if (p+1 < p1) proc(hA1, vA1);
            if (p+2 < p1) proc(hA2, vA2);
            if (p+3 < p1) proc(hA3, vA3);
            p += 4;
            if (p >= p1) break;
            ld(p+4, hA0, vA0); ld(p+5, hA1, vA1); ld(p+6, hA2, vA2); ld(p+7, hA3, vA3);
            proc(hB0, vB0);
            if (p+1 < p1) proc(hB1, vB1);
            if (p+2 < p1) proc(hB2, vB2);
            if (p+3 < p1) proc(hB3, vB3);
            p += 4;
        }

        float inv = 1.f/(s + 1e-16f);
        float o0 = acc0*inv + bj0;
        float o1 = (EL==2) ? acc1*inv + bj1 : 0.f;
        if (STATS){ ls0+=o0; lq0+=o0*o0; ls1+=o1; lq1+=o1*o1; }
        if (!DECODE){
            if (EL==2) *(float2*)(z + (size_t)dst*M + j) = make_float2(o0,o1);
            else       z[(size_t)dst*M + j] = o0;
        } else {
            float a0=o0*w0, a1=o0*w1, a2=o0*w2, a3=o0*w3;
            #pragma unroll
            for (int off=32; off; off>>=1){
                a0 += __shfl_xor(a0, off, 64);
                a1 += __shfl_xor(a1, off, 64);
                a2 += __shfl_xor(a2, off, 64);
                a3 += __shfl_xor(a3, off, 64);
            }
            if (lane == 0){
                float4 o = make_float4(a0+decb[0], a1+decb[1], a2+decb[2], a3+decb[3]);
                *(float4*)(out + (size_t)dst*4) = o;
            }
        }
    }
    if (STATS){
        __shared__ float sls[128], slq[128];
        if (threadIdx.x < 128){ sls[threadIdx.x]=0.f; slq[threadIdx.x]=0.f; }
        __syncthreads();
        atomicAdd(&sls[j], ls0);  atomicAdd(&slq[j], lq0);
        if (EL==2){ atomicAdd(&sls[j+1], ls1); atomicAdd(&slq[j+1], lq1); }
        __syncthreads();
        if (threadIdx.x < 128){
            atomicAdd(cs + threadIdx.x, sls[threadIdx.x]);
            atomicAdd(cq + threadIdx.x, slq[threadIdx.x]);
        }
    }
}

extern "C" void kernel_launch(void* const* d_in, const int* in_sizes, int n_in,
                              void* d_out, int out_size, void* d_ws, size_t ws_size,
                              hipStream_t stream){
    const float* x      = (const float*)d_in[0];
    const int*   ei     = (const int*)  d_in[1];
    const float* enc_W  = (const float*)d_in[2];
    const float* enc_b  = (const float*)d_in[3];
    const float* in_W   = (const float*)d_in[4];
    const float* in_as  = (const float*)d_in[5];
    const float* in_ad  = (const float*)d_in[6];
    const float* in_b   = (const float*)d_in[7];
    const float* hid_W  = (const float*)d_in[8];
    const float* hid_as = (const float*)d_in[9];
    const float* hid_ad = (const float*)d_in[10];
    const float* hid_b  = (const float*)d_in[11];
    const float* bn_g   = (const float*)d_in[12];
    const float* bn_b   = (const float*)d_in[13];
    const float* out_W  = (const float*)d_in[14];
    const float* out_as = (const float*)d_in[15];
    const float* out_ad = (const float*)d_in[16];
    const float* out_b  = (const float*)d_in[17];
    const float* dec_W  = (const float*)d_in[18];
    const float* dec_b  = (const float*)d_in[19];

    const int N = in_sizes[0] / 7;
    const int E = in_sizes[1] / 2;
    const int NB = (N + 1023) / 1024;
    const int NT = (N + 63) / 64;
    const int AGG_BLOCKS = 2048, TOT_WAVES = AGG_BLOCKS*4;

    // workspace layout:
    float*    bufZ   = (float*)d_ws;                  // [N,128] fp32 activations
    float*    al_s   = bufZ + (size_t)N*128;          // [N,4]
    float*    al_d   = al_s + (size_t)N*4;            // [N,4]
    float*    cs     = al_d + (size_t)N*4;            // [128]
    float*    cq     = cs + 128;                      // [128]
    float*    scale  = cq + 128;                      // [128]
    float*    shift  = scale + 128;                   // [128]
    int*      deg    = (int*)(shift + 128);           // [N]
    int*      excl   = deg + N;                       // [N]
    int*      rowptr = excl + N;                      // [N+1]
    int*      cursor = rowptr + (N+1);                // [N]
    int*      bsum   = cursor + N;                    // [NB]
    int*      csr    = bsum + NB;                     // [E]
    u16*      hb     = (u16*)(((uintptr_t)(csr + E) + 15) & ~(uintptr_t)15); // [N,128] bf16
    u16*      wk     = hb + (size_t)N*128;
    u16* wk_in_hi  = wk;                    u16* wk_in_lo  = wk_in_hi  + 64*128;
    u16* wk_h0_hi  = wk_in_lo  + 64*128;    u16* wk_h0_lo  = wk_h0_hi  + 128*128;
    u16* wk_h1_hi  = wk_h0_lo  + 128*128;   u16* wk_h1_lo  = wk_h1_hi  + 128*128;
    u16* wk_out_hi = wk_h1_lo  + 128*128;   u16* wk_out_lo = wk_out_hi + 128*64;

    // ---- pack weights ----
    k_pack_w<64,128><<<(64*128+255)/256, 256, 0, stream>>>(in_W, wk_in_hi, wk_in_lo);
    k_pack_w<128,128><<<(128*128+255)/256, 256, 0, stream>>>(hid_W, wk_h0_hi, wk_h0_lo);
    k_pack_w<128,128><<<(128*128+255)/256, 256, 0, stream>>>(hid_W + 128*128, wk_h1_hi, wk_h1_lo);
    k_pack_w<128,64><<<(128*64+255)/256, 256, 0, stream>>>(out_W, wk_out_hi, wk_out_lo);

    // ---- CSR build ----
    hipMemsetAsync(deg, 0, (size_t)N*sizeof(int), stream);
    k_deg   <<<(E+255)/256, 256, 0, stream>>>(ei, E, deg);
    k_scan1 <<<NB, 1024, 0, stream>>>(deg, excl, bsum, N);
    k_scan2 <<<1, 64, 0, stream>>>(bsum, NB);
    k_scan3 <<<(N+1+255)/256, 256, 0, stream>>>(excl, bsum, rowptr, cursor, N, E);
    k_bucket<<<(E+255)/256, 256, 0, stream>>>(ei, E, cursor, csr);

    // ---- encoder ----
    k_encoder<<<(N*64+255)/256, 256, 0, stream>>>(x, enc_W, enc_b, bufZ, N);

    const float invN = 1.f/(float)N;

    // ---- GAT layer 1 (K=64, no input BN) ----
    k_gemm<64,128,2,2,2,4,4,false><<<NT, 256, 0, stream>>>(bufZ, wk_in_hi, wk_in_lo,
            nullptr, nullptr, in_as, in_ad, hb, al_s, al_d, N);
    hipMemsetAsync(cs, 0, 256*sizeof(float), stream);
    k_gat_agg<4,32,true,false><<<AGG_BLOCKS, 256, 0, stream>>>(rowptr, csr, al_s, al_d,
            hb, in_b, bufZ, cs, cq, nullptr, nullptr, nullptr, N, TOT_WAVES);
    k_bn_coef<<<1, 128, 0, stream>>>(cs, cq, bn_g, bn_b, scale, shift, invN);

    // ---- hidden GAT layers (input BN+ReLU fused into GEMM staging) ----
    for (int i = 0; i < 2; i++){
        const u16* whi = i ? wk_h1_hi : wk_h0_hi;
        const u16* wlo = i ? wk_h1_lo : wk_h0_lo;
        k_gemm<128,128,2,2,2,4,4,true><<<NT, 256, 0, stream>>>(bufZ, whi, wlo,
                scale, shift, hid_as + (size_t)i*128, hid_ad + (size_t)i*128,
                hb, al_s, al_d, N);
        hipMemsetAsync(cs, 0, 256*sizeof(float), stream);
        k_gat_agg<4,32,true,false><<<AGG_BLOCKS, 256, 0, stream>>>(rowptr, csr, al_s, al_d,
                hb, hid_b + (size_t)i*128, bufZ, cs, cq, nullptr, nullptr, nullptr, N, TOT_WAVES);
        k_bn_coef<<<1, 128, 0, stream>>>(cs, cq, bn_g + (i+1)*128, bn_b + (i+1)*128, scale, shift, invN);
    }

    // ---- out GAT layer (K=128 -> 1x64) + fused decoder ----
    k_gemm<128,64,4,1,1,4,1,true><<<NT, 256, 0, stream>>>(bufZ, wk_out_hi, wk_out_lo,
            scale, shift, out_as, out_ad, hb, al_s, al_d, N);
    k_gat_agg<1,64,false,true><<<AGG_BLOCKS, 256, 0, stream>>>(rowptr, csr, al_s, al_d,
            hb, out_b, nullptr, nullptr, nullptr, dec_W, dec_b, (float*)d_out, N, TOT_WAVES);
}